// Round 16
// baseline (348.721 us; speedup 1.0000x reference)
//
#include <hip/hip_runtime.h>
#include <hip/hip_bf16.h>
#include <math.h>

#define T_DIM 2048
#define D_DIM 2048
#define H_DIM 16
#define C_DIM 128

typedef __bf16 bf16;
typedef __attribute__((ext_vector_type(8))) __bf16 bf16x8;
typedef __attribute__((ext_vector_type(4))) __bf16 bf16x4;
typedef __attribute__((ext_vector_type(2))) __bf16 bf16x2;
typedef __attribute__((ext_vector_type(4))) float f32x4;

__device__ __forceinline__ void gload_lds16(const void* g, void* l) {
  __builtin_amdgcn_global_load_lds((__attribute__((address_space(1))) void*)g,
                                   (__attribute__((address_space(3))) void*)l,
                                   16, 0, 0);
}

// ---------------- fused fp32 -> bf16 conversion of x, W_attn, W_proj ----------------
__global__ __launch_bounds__(256) void cvt3(
    const float* __restrict__ x, const float* __restrict__ wa, const float* __restrict__ wp,
    bf16* __restrict__ xo, bf16* __restrict__ wao, bf16* __restrict__ wpo)
{
  const int NX = 1048576, NA = 3145728;      // float4 counts: x, W_attn (W_proj = NX)
  int i = blockIdx.x * 256 + threadIdx.x;
  for (; i < 5242880; i += 2048 * 256) {
    const float* s; bf16* d; int off;
    if (i < NX)            { s = x;  d = xo;  off = i; }
    else if (i < NX + NA)  { s = wa; d = wao; off = i - NX; }
    else                   { s = wp; d = wpo; off = i - NX - NA; }
    float4 v = reinterpret_cast<const float4*>(s)[off];
    bf16x4 o;
    o[0] = (bf16)v.x; o[1] = (bf16)v.y; o[2] = (bf16)v.z; o[3] = (bf16)v.w;
    reinterpret_cast<bf16x4*>(d)[off] = o;
  }
}

// ============ 128x384 fat-phase GEMM: C = A(MxK) @ B(NxK)^T + bias ============
template <typename OutT>
__global__ __launch_bounds__(512, 2) void gemm384_bt_bias(
    const bf16* __restrict__ A, const bf16* __restrict__ B,
    const float* __restrict__ bias, OutT* __restrict__ C,
    int M, int N, int K)
{
  __shared__ __align__(16) bf16 Asl[2][128 * 64];  // 32 KB
  __shared__ __align__(16) bf16 Bsl[2][384 * 64];  // 96 KB
  const int tid = threadIdx.x;
  const int lane = tid & 63;
  const int wv = tid >> 6;          // 0..7
  const int g = lane >> 4, r16 = lane & 15;
  const int wm = wv >> 2;           // 0..1 : 64-row slice
  const int wn = wv & 3;            // 0..3 : 96-col slice

  int bid = blockIdx.x;
  int bid2 = (bid & 7) * (gridDim.x >> 3) + (bid >> 3);
  const int ntn = N / 384;
  const int bn = bid2 % ntn, bm = bid2 / ntn;

  const size_t Abase = (size_t)(bm * 128) * K;
  const size_t Bbase = (size_t)(bn * 384) * K;

  f32x4 acc[2][2][2][3] = {};          // [qr][qc][R][F]
  bf16x8 a0[2][2], a1[2][2];           // A row-halves  [R][ks]
  bf16x8 b0[3][2], b1[3][2];           // B col-halves  [F][ks]

  auto stageA = [&](int bb, int t) {
#pragma unroll
    for (int i = 0; i < 2; ++i) {
      int c = i * 512 + tid;
      int r = c >> 3, p = c & 7, j = p ^ (r & 7);
      gload_lds16(A + Abase + (size_t)r * K + t * 64 + j * 8,
                  (char*)&Asl[bb][0] + (size_t)c * 16);
    }
  };
  auto stageB = [&](int bb, int u, int t) {   // u = 0..2 -> B rows u*128..+127
#pragma unroll
    for (int i = 0; i < 2; ++i) {
      int c = i * 512 + tid;
      int r = c >> 3, p = c & 7, j = p ^ (r & 7);
      gload_lds16(B + Bbase + (size_t)(u * 128 + r) * K + t * 64 + j * 8,
                  (char*)&Bsl[bb][0] + u * 16384 + (size_t)c * 16);
    }
  };
  auto readAh = [&](bf16x8 (&dst)[2][2], int bufi, int qr) {
#pragma unroll
    for (int R = 0; R < 2; ++R) {
      int ar = wm * 64 + qr * 32 + R * 16 + r16;
#pragma unroll
      for (int ks = 0; ks < 2; ++ks)
        dst[R][ks] = *reinterpret_cast<const bf16x8*>(
            &Asl[bufi][ar * 64 + (((ks * 4 + g) ^ (ar & 7)) << 3)]);
    }
  };
  auto readBh = [&](bf16x8 (&dst)[3][2], int bufi, int qc) {
#pragma unroll
    for (int F = 0; F < 3; ++F) {
      int br = wn * 96 + qc * 48 + F * 16 + r16;
#pragma unroll
      for (int ks = 0; ks < 2; ++ks)
        dst[F][ks] = *reinterpret_cast<const bf16x8*>(
            &Bsl[bufi][br * 64 + (((ks * 4 + g) ^ (br & 7)) << 3)]);
    }
  };
  auto mfma12 = [&](f32x4 (&cq)[2][3], bf16x8 (&aa)[2][2], bf16x8 (&bb)[3][2]) {
#pragma unroll
    for (int ks = 0; ks < 2; ++ks)
#pragma unroll
      for (int R = 0; R < 2; ++R)
#pragma unroll
        for (int F = 0; F < 3; ++F)
          cq[R][F] = __builtin_amdgcn_mfma_f32_16x16x32_bf16(aa[R][ks], bb[F][ks], cq[R][F], 0, 0, 0);
  };

  stageA(0, 0); stageB(0, 0, 0); stageB(0, 1, 0); stageB(0, 2, 0);
  __syncthreads();

  const int NT = K >> 6;
  for (int t = 0; t < NT; ++t) {
    const int cb = t & 1, nb = cb ^ 1;
    if (t + 1 < NT) {
      stageA(nb, t + 1); stageB(nb, 0, t + 1); stageB(nb, 1, t + 1); stageB(nb, 2, t + 1);
    }
    readAh(a0, cb, 0); readAh(a1, cb, 1);
    readBh(b0, cb, 0); readBh(b1, cb, 1);
    mfma12(acc[0][0], a0, b0);
    mfma12(acc[0][1], a0, b1);
    mfma12(acc[1][1], a1, b1);
    mfma12(acc[1][0], a1, b0);
    __syncthreads();
  }

#pragma unroll
  for (int qr = 0; qr < 2; ++qr)
#pragma unroll
    for (int qc = 0; qc < 2; ++qc)
#pragma unroll
      for (int R = 0; R < 2; ++R)
#pragma unroll
        for (int F = 0; F < 3; ++F) {
          int row0 = bm * 128 + wm * 64 + qr * 32 + R * 16 + g * 4;
          int col  = bn * 384 + wn * 96 + qc * 48 + F * 16 + r16;
          float bv = bias[col];
#pragma unroll
          for (int rr = 0; rr < 4; ++rr)
            C[(size_t)(row0 + rr) * N + col] = (OutT)(acc[qr][qc][R][F][rr] + bv);
        }
}

// ---------------- 128x128 fat-phase GEMM (BK=64 dbuf, 2 blocks/CU): fp32 out --------
__global__ __launch_bounds__(256, 2) void gemm_bt_bias(
    const bf16* __restrict__ A, const bf16* __restrict__ B,
    const float* __restrict__ bias, float* __restrict__ C,
    int M, int N, int K)
{
  __shared__ __align__(16) bf16 As[2][128 * 64];  // 32 KB
  __shared__ __align__(16) bf16 Bs[2][128 * 64];  // 32 KB
  const int tid = threadIdx.x;
  const int lane = tid & 63;
  const int w = tid >> 6;
  const int wm = (w >> 1) * 64, wn = (w & 1) * 64;
  const int g = lane >> 4;
  const int r16 = lane & 15;

  int lb = blockIdx.y * gridDim.x + blockIdx.x;
  int nblk = gridDim.x * gridDim.y;
  int s = (lb & 7) * (nblk >> 3) + (lb >> 3);
  const int bn = s % gridDim.x, bm = s / gridDim.x;

  f32x4 acc[4][4] = {};

  const size_t Abase = (size_t)(bm * 128) * K;
  const size_t Bbase = (size_t)(bn * 128) * K;

  auto stage = [&](int bb, int t) {
#pragma unroll
    for (int i = 0; i < 4; ++i) {
      int c = i * 256 + tid;
      int r = c >> 3, p = c & 7, j = p ^ (r & 7);
      gload_lds16(A + Abase + (size_t)r * K + t * 64 + j * 8,
                  (char*)&As[bb][0] + (size_t)c * 16);
      gload_lds16(B + Bbase + (size_t)r * K + t * 64 + j * 8,
                  (char*)&Bs[bb][0] + (size_t)c * 16);
    }
  };

  stage(0, 0);
  __syncthreads();

  const int NT = K >> 6;
  for (int t = 0; t < NT; ++t) {
    const int cb = t & 1, nb = cb ^ 1;
    if (t + 1 < NT) stage(nb, t + 1);
    bf16x8 a[4][2], b[4][2];
#pragma unroll
    for (int m = 0; m < 4; ++m) {
      int ar = wm + m * 16 + r16;
#pragma unroll
      for (int ks = 0; ks < 2; ++ks)
        a[m][ks] = *reinterpret_cast<const bf16x8*>(
            &As[cb][ar * 64 + (((ks * 4 + g) ^ (ar & 7)) << 3)]);
    }
#pragma unroll
    for (int n = 0; n < 4; ++n) {
      int br = wn + n * 16 + r16;
#pragma unroll
      for (int ks = 0; ks < 2; ++ks)
        b[n][ks] = *reinterpret_cast<const bf16x8*>(
            &Bs[cb][br * 64 + (((ks * 4 + g) ^ (br & 7)) << 3)]);
    }
#pragma unroll
    for (int ks = 0; ks < 2; ++ks)
#pragma unroll
      for (int m = 0; m < 4; ++m)
#pragma unroll
        for (int n = 0; n < 4; ++n)
          acc[m][n] = __builtin_amdgcn_mfma_f32_16x16x32_bf16(a[m][ks], b[n][ks], acc[m][n], 0, 0, 0);
    __syncthreads();
  }

#pragma unroll
  for (int m = 0; m < 4; ++m) {
    int row0 = bm * 128 + wm + m * 16 + g * 4;
#pragma unroll
    for (int n = 0; n < 4; ++n) {
      int col = bn * 128 + wn + n * 16 + r16;
      float bv = bias[col];
#pragma unroll
      for (int rr = 0; rr < 4; ++rr)
        C[(size_t)(row0 + rr) * N + col] = acc[m][n][rr] + bv;
    }
  }
}

// -------- fused LayerNorm+RoPE (blocks 0..4095) + V transpose (blocks 4096..8191) ----
__global__ __launch_bounds__(256) void lnrope_vt_kernel(
    const bf16* __restrict__ qkv, const float* __restrict__ qw,
    const float* __restrict__ kw, bf16* __restrict__ qo, bf16* __restrict__ ko,
    bf16* __restrict__ vt)
{
  __shared__ bf16 tile[32][36];
  const int tid = threadIdx.x;
  if (blockIdx.x < 4096) {
    const int lane = tid & 63;
    const int wid = blockIdx.x * 4 + (tid >> 6);   // 0..16383
    const int rid = wid * 2 + (lane >> 5);         // 0..32767
    const int h = rid >> 11;
    const int t = rid & (T_DIM - 1);
    const int c0 = (lane & 31) * 4;

    float if0 = exp2f(-13.287712379549449f * (float)c0 * (1.0f / 128.0f));
    float if1 = exp2f(-13.287712379549449f * (float)(c0 + 2) * (1.0f / 128.0f));
    float fr0 = (float)t * if0, fr1 = (float)t * if1;
    float sn0 = sinf(fr0), cs0 = cosf(fr0);
    float sn1 = sinf(fr1), cs1 = cosf(fr1);
    const float scaleq = 0.08838834764831845f; // 1/sqrt(128)

#pragma unroll
    for (int which = 0; which < 2; ++which) {
      const bf16* base = qkv + (size_t)t * (3 * D_DIM) + which * D_DIM + h * C_DIM + c0;
      bf16x4 v4 = *reinterpret_cast<const bf16x4*>(base);
      float x0 = (float)v4[0], x1 = (float)v4[1], x2 = (float)v4[2], x3 = (float)v4[3];
      float s = x0 + x1 + x2 + x3;
#pragma unroll
      for (int m = 16; m; m >>= 1) s += __shfl_xor(s, m);
      float mu = s * (1.0f / 128.0f);
      float d0 = x0 - mu, d1 = x1 - mu, d2 = x2 - mu, d3 = x3 - mu;
      float ss = d0 * d0 + d1 * d1 + d2 * d2 + d3 * d3;
#pragma unroll
      for (int m = 16; m; m >>= 1) ss += __shfl_xor(ss, m);
      float rstd = rsqrtf(ss * (1.0f / 128.0f) + 1e-6f);
      const float* wgt = which ? kw : qw;
      float4 wv = *reinterpret_cast<const float4*>(wgt + c0);
      float y0 = d0 * rstd * wv.x, y1 = d1 * rstd * wv.y;
      float y2 = d2 * rstd * wv.z, y3 = d3 * rstd * wv.w;
      float o0 = y0 * cs0 - y1 * sn0;
      float o1 = y1 * cs0 + y0 * sn0;
      float o2 = y2 * cs1 - y3 * sn1;
      float o3 = y3 * cs1 + y2 * sn1;
      if (!which) { o0 *= scaleq; o1 *= scaleq; o2 *= scaleq; o3 *= scaleq; }
      bf16x4 ob; ob[0] = (bf16)o0; ob[1] = (bf16)o1; ob[2] = (bf16)o2; ob[3] = (bf16)o3;
      *reinterpret_cast<bf16x4*>(
          (which ? ko : qo) + ((size_t)h * T_DIM + t) * C_DIM + c0) = ob;
    }
  } else {
    const int vb = blockIdx.x - 4096;          // 64 x 4 x 16
    const int t0 = (vb & 63) * 32;
    const int c0 = ((vb >> 6) & 3) * 32;
    const int h = vb >> 8;
    {
      int row = tid >> 3, col4 = (tid & 7) * 4;
      *reinterpret_cast<bf16x4*>(&tile[row][col4]) =
          *reinterpret_cast<const bf16x4*>(
              &qkv[(size_t)(t0 + row) * (3 * D_DIM) + 2 * D_DIM + h * C_DIM + c0 + col4]);
    }
    __syncthreads();
    {
      int c = tid >> 3, t4 = (tid & 7) * 4;
      bf16x4 ob;
      ob[0] = tile[t4][c];     ob[1] = tile[t4 + 1][c];
      ob[2] = tile[t4 + 2][c]; ob[3] = tile[t4 + 3][c];
      *reinterpret_cast<bf16x4*>(
          &vt[((size_t)h * C_DIM + c0 + c) * T_DIM + t0 + t4]) = ob;
    }
  }
}

// ------- Flash attention (causal): R8 body, SINGLE-buffer K/V, 8 blocks/CU -------
// LDS 20 KB (K 8 + V 8 + p_lds 4) -> 8 blocks/CU = 32 waves/CU (VGPR 56 <= 64 cap).
// Per iter: vmcnt(0)+barrier (stage landed), compute, syncthreads, issue next stage.
// Exposed stage latency is hidden by cross-block TLP (the only lever that ever moved
// attn: R2->R3 was a 2x-waves win; all fixed-TLP scheduling variants were null).
// Grid: 144 blocks/head x 16 heads = 2304 (fills 8/CU). Segments of <= 8 KV-tiles:
//   b < 4: qb = b, direct. b >= 4: group g=0..6, qb in [4+4g, 7+4g], nseg = g+2,
//   cum(g) = 4 + 2g^2 + 6g. Partial U (bf16) slot = h*140 + (b-4).
__global__ __launch_bounds__(256, 8) void attn_kernel(
    const bf16* __restrict__ Q, const bf16* __restrict__ K,
    const bf16* __restrict__ VT, bf16* __restrict__ AO,
    bf16* __restrict__ U, float* __restrict__ ML)
{
  __shared__ __align__(16) bf16 Ks[32 * 128];      // 8 KB
  __shared__ __align__(16) bf16 Vs[128 * 32];      // 8 KB
  __shared__ __align__(16) bf16 p_lds[4][16 * 32]; // 4 KB
  const int tid = threadIdx.x;
  const int lane = tid & 63;
  const int w = tid >> 6;
  const int g = lane >> 4, r16 = lane & 15;
  const int h = blockIdx.y;
  const int b = blockIdx.x;

  int qb, sp, nseg;
  if (b < 4) { qb = b; sp = -1; nseg = 1; }
  else {
    int gg = 0, cum = 4;
    while (b >= cum + 4 * (gg + 2)) { cum += 4 * (gg + 2); ++gg; }
    int off = b - cum;
    nseg = gg + 2;
    qb = 4 + 4 * gg + off / nseg;
    sp = off % nseg;
  }
  const int ntile = 2 * qb + 2;
  const int kb0 = (sp < 0) ? 0 : (ntile * sp) / nseg;
  const int kb1 = (sp < 0) ? ntile : (ntile * (sp + 1)) / nseg;

  const int qr0 = qb * 64 + w * 16;
  const int qrow = qr0 + r16;   // this lane's q-row

  const bf16* Qh = Q + (size_t)h * T_DIM * C_DIM;
  const bf16* Kh = K + (size_t)h * T_DIM * C_DIM;
  const bf16* Vh = VT + (size_t)h * C_DIM * T_DIM;

  bf16x8 qf[4];
#pragma unroll
  for (int kk = 0; kk < 4; ++kk)
    qf[kk] = *reinterpret_cast<const bf16x8*>(
        &Qh[(size_t)qrow * C_DIM + kk * 32 + g * 8]);

  float mrow = -INFINITY, lrow = 0.f;
  f32x4 o[8] = {};

  auto stage = [&](int kb) {
    const bf16* Kt = Kh + (size_t)(kb * 32) * C_DIM;
    const bf16* Vt = Vh + kb * 32;
#pragma unroll
    for (int i = 0; i < 2; ++i) {
      int e = i * 256 + tid;
      int r = e >> 4, p = e & 15, j = p ^ (r & 7);
      gload_lds16(Kt + r * C_DIM + j * 8, (char*)&Ks[0] + (size_t)e * 16);
    }
#pragma unroll
    for (int i = 0; i < 2; ++i) {
      int e = i * 256 + tid;
      int r = e >> 2, p = e & 3, j = p ^ ((r >> 1) & 3);
      gload_lds16(Vt + (size_t)r * T_DIM + j * 8, (char*)&Vs[0] + (size_t)e * 16);
    }
  };

  stage(kb0);

  for (int kb = kb0; kb < kb1; ++kb) {
    asm volatile("s_waitcnt vmcnt(0)" ::: "memory");
    __builtin_amdgcn_s_barrier();          // tile staged for all waves
    __builtin_amdgcn_sched_barrier(0);

    f32x4 sacc[2] = {};
    __builtin_amdgcn_s_setprio(1);
#pragma unroll
    for (int n = 0; n < 2; ++n) {
      int kr = n * 16 + r16;
      const bf16* kbase = &Ks[kr << 7];
#pragma unroll
      for (int kk = 0; kk < 4; ++kk) {
        bf16x8 kf = *reinterpret_cast<const bf16x8*>(
            kbase + (((kk * 4 + g) ^ (kr & 7)) << 3));
        sacc[n] = __builtin_amdgcn_mfma_f32_16x16x32_bf16(kf, qf[kk], sacc[n], 0, 0, 0);
      }
    }
    __builtin_amdgcn_s_setprio(0);
    if (kb * 32 + 31 > qr0) {
#pragma unroll
      for (int n = 0; n < 2; ++n)
#pragma unroll
        for (int rr = 0; rr < 4; ++rr)
          if (kb * 32 + n * 16 + g * 4 + rr > qrow) sacc[n][rr] = -3.0e38f;
    }
    float mx = fmaxf(fmaxf(fmaxf(sacc[0][0], sacc[0][1]), fmaxf(sacc[0][2], sacc[0][3])),
                     fmaxf(fmaxf(sacc[1][0], sacc[1][1]), fmaxf(sacc[1][2], sacc[1][3])));
    mx = fmaxf(mx, __shfl_xor(mx, 16));
    mx = fmaxf(mx, __shfl_xor(mx, 32));
    float alpha = 1.0f;
    bool need = __any(mx > mrow + 8.0f);  // T13 defer-rescale
    if (need) {
      float mnew = fmaxf(mrow, mx);
      alpha = __expf(mrow - mnew);
      mrow = mnew;
    }
    float ps = 0.f;
#pragma unroll
    for (int n = 0; n < 2; ++n)
#pragma unroll
      for (int rr = 0; rr < 4; ++rr) {
        float p = __expf(sacc[n][rr] - mrow);
        sacc[n][rr] = p;
        ps += p;
      }
    ps += __shfl_xor(ps, 16);
    ps += __shfl_xor(ps, 32);
    lrow = lrow * alpha + ps;
    if (need) {
#pragma unroll
      for (int nc = 0; nc < 8; ++nc)
#pragma unroll
        for (int rr = 0; rr < 4; ++rr)
          o[nc][rr] *= alpha;
    }
    {
      bf16* prow = &p_lds[w][r16 << 5];
      const int ssw = (r16 >> 1) & 3;
#pragma unroll
      for (int n = 0; n < 2; ++n) {
        bf16x4 pk;
        pk[0] = (bf16)sacc[n][0]; pk[1] = (bf16)sacc[n][1];
        pk[2] = (bf16)sacc[n][2]; pk[3] = (bf16)sacc[n][3];
        int c8 = 2 * n + (g >> 1);
        *reinterpret_cast<bf16x4*>(prow + (((c8 ^ ssw) << 3) | ((g & 1) << 2))) = pk;
      }
    }
    asm volatile("s_waitcnt lgkmcnt(0)" ::: "memory");
    __builtin_amdgcn_s_setprio(1);
    bf16x8 pf = *reinterpret_cast<const bf16x8*>(
        &p_lds[w][(r16 << 5) + ((g ^ ((r16 >> 1) & 3)) << 3)]);
#pragma unroll
    for (int nc = 0; nc < 8; ++nc) {
      int vr = nc * 16 + r16;
      bf16x8 vf = *reinterpret_cast<const bf16x8*>(
          &Vs[(vr << 5) + ((g ^ ((vr >> 1) & 3)) << 3)]);
      o[nc] = __builtin_amdgcn_mfma_f32_16x16x32_bf16(vf, pf, o[nc], 0, 0, 0);
    }
    __builtin_amdgcn_s_setprio(0);
    __syncthreads();                       // all reads done before overwrite
    if (kb + 1 < kb1) stage(kb + 1);       // issue next tile
  }

  if (sp < 0) {
    float inv = 1.0f / lrow;
    bf16* arow = &AO[(size_t)qrow * D_DIM + h * C_DIM + (g << 2)];
#pragma unroll
    for (int nc = 0; nc < 8; ++nc) {
      bf16x4 ob;
      ob[0] = (bf16)(o[nc][0] * inv); ob[1] = (bf16)(o[nc][1] * inv);
      ob[2] = (bf16)(o[nc][2] * inv); ob[3] = (bf16)(o[nc][3] * inv);
      *reinterpret_cast<bf16x4*>(arow + nc * 16) = ob;
    }
  } else {
    // partial: U bf16, slot = h*140 + (b-4)
    const int slot = h * 140 + (b - 4);
    const size_t ubase = (size_t)slot * (64 * 128);
    const size_t mlb = (size_t)slot * 128;
    const int row = w * 16 + r16;          // 0..63
    bf16* urow = &U[ubase + (size_t)row * 128 + (g << 2)];
#pragma unroll
    for (int nc = 0; nc < 8; ++nc) {
      bf16x4 ub;
      ub[0] = (bf16)o[nc][0]; ub[1] = (bf16)o[nc][1];
      ub[2] = (bf16)o[nc][2]; ub[3] = (bf16)o[nc][3];
      *reinterpret_cast<bf16x4*>(urow + nc * 16) = ub;
    }
    if (g == 0) {
      ML[mlb + row] = mrow;
      ML[mlb + 64 + row] = lrow;
    }
  }
}

// ---------- combine: merge 2..8 KV-split partials for qb in [4,32) ----------
__global__ __launch_bounds__(256) void attn_combine(
    const bf16* __restrict__ U, const float* __restrict__ ML, bf16* __restrict__ AO)
{
  int idx = blockIdx.x * 256 + threadIdx.x;  // 917504 = 16h x 28qi x 64row x 32c4
  int c4 = (idx & 31) * 4;
  int r = idx >> 5;
  int trow = r & 63;
  int hq = r >> 6;             // h*28 + qi, qb = qi + 4
  int qi = hq % 28;
  int h = hq / 28;
  int g = qi >> 2;             // group 0..6
  int nseg = g + 2;
  int slot0 = h * 140 + (2 * g * g + 6 * g) + (qi - 4 * g) * nseg;

  float m = -INFINITY;
  for (int s = 0; s < nseg; ++s)
    m = fmaxf(m, ML[(size_t)(slot0 + s) * 128 + trow]);
  float L = 0.f;
  float ox = 0.f, oy = 0.f, oz = 0.f, ow = 0.f;
  for (int s = 0; s < nseg; ++s) {
    size_t mlb = (size_t)(slot0 + s) * 128;
    float a = __expf(ML[mlb + trow] - m);
    L += ML[mlb + 64 + trow] * a;
    bf16x4 u = *reinterpret_cast<const bf16x4*>(
        U + (size_t)(slot0 + s) * (64 * 128) + (size_t)trow * 128 + c4);
    ox += (float)u[0] * a; oy += (float)u[1] * a;
    oz += (float)u[2] * a; ow += (float)u[3] * a;
  }
  float inv = 1.0f / L;
  int t = (qi + 4) * 64 + trow;
  bf16x4 ob;
  ob[0] = (bf16)(ox * inv); ob[1] = (bf16)(oy * inv);
  ob[2] = (bf16)(oz * inv); ob[3] = (bf16)(ow * inv);
  *reinterpret_cast<bf16x4*>(&AO[(size_t)t * D_DIM + h * C_DIM + c4]) = ob;
}

// ---------------- launch ----------------
extern "C" void kernel_launch(void* const* d_in, const int* in_sizes, int n_in,
                              void* d_out, int out_size, void* d_ws, size_t ws_size,
                              hipStream_t stream)
{
  const float* x      = (const float*)d_in[0];
  const float* W_attn = (const float*)d_in[1];
  const float* b_attn = (const float*)d_in[2];
  const float* W_proj = (const float*)d_in[3];
  const float* b_proj = (const float*)d_in[4];
  const float* q_ln_w = (const float*)d_in[5];
  const float* k_ln_w = (const float*)d_in[6];

  char* ws = (char*)d_ws;
  bf16*  x_bf  = (bf16*)(ws + 0);           //  8 MB
  bf16*  wa_bf = (bf16*)(ws + 8388608);     // 24 MB
  bf16*  wp_bf = (bf16*)(ws + 33554432);    //  8 MB (live until proj GEMM)
  bf16*  qkv   = (bf16*)(ws + 41943040);    // 24 MB (dead after lnrope_vt)
  bf16*  q_bf  = (bf16*)(ws + 92274688);    //  8 MB
  bf16*  k_bf  = (bf16*)(ws + 100663296);   //  8 MB
  bf16*  vt    = (bf16*)(ws + 109051904);   //  8 MB
  bf16*  ao    = (bf16*)(ws + 117440512);   //  8 MB (total 120 MB)
  // U/ML alias the dead qkv + old-U region (attn runs after lnrope_vt)
  bf16*  U  = (bf16*)(ws + 41943040);       // 36.7 MB: 2240 slots x 64x128 bf16
  float* ML = (float*)(ws + 78643200);      // 1.1 MB: 2240 x 128 f32

  cvt3<<<2048, 256, 0, stream>>>(x, W_attn, W_proj, x_bf, wa_bf, wp_bf);

  gemm384_bt_bias<bf16><<<dim3((T_DIM / 128) * (3 * D_DIM / 384)), dim3(512), 0, stream>>>(
      x_bf, wa_bf, b_attn, qkv, T_DIM, 3 * D_DIM, D_DIM);

  lnrope_vt_kernel<<<4096 + 4096, 256, 0, stream>>>(qkv, q_ln_w, k_ln_w, q_bf, k_bf, vt);

  attn_kernel<<<dim3(144, H_DIM), 256, 0, stream>>>(q_bf, k_bf, vt, ao, U, ML);
  attn_combine<<<3584, 256, 0, stream>>>(U, ML, ao);

  gemm_bt_bias<<<dim3(D_DIM / 128, T_DIM / 128), 256, 0, stream>>>(
      ao, wp_bf, b_proj, (float*)d_out, T_DIM, D_DIM, D_DIM);
}

// Round 17
// 167.500 us; speedup vs baseline: 2.0819x; 2.0819x over previous
//
#include <hip/hip_runtime.h>
#include <hip/hip_bf16.h>
#include <math.h>

#define T_DIM 2048
#define D_DIM 2048
#define H_DIM 16
#define C_DIM 128

typedef __bf16 bf16;
typedef __attribute__((ext_vector_type(8))) __bf16 bf16x8;
typedef __attribute__((ext_vector_type(4))) __bf16 bf16x4;
typedef __attribute__((ext_vector_type(2))) __bf16 bf16x2;
typedef __attribute__((ext_vector_type(4))) float f32x4;

__device__ __forceinline__ void gload_lds16(const void* g, void* l) {
  __builtin_amdgcn_global_load_lds((__attribute__((address_space(1))) void*)g,
                                   (__attribute__((address_space(3))) void*)l,
                                   16, 0, 0);
}

// ---------------- fused fp32 -> bf16 conversion of x, W_attn, W_proj ----------------
__global__ __launch_bounds__(256) void cvt3(
    const float* __restrict__ x, const float* __restrict__ wa, const float* __restrict__ wp,
    bf16* __restrict__ xo, bf16* __restrict__ wao, bf16* __restrict__ wpo)
{
  const int NX = 1048576, NA = 3145728;      // float4 counts: x, W_attn (W_proj = NX)
  int i = blockIdx.x * 256 + threadIdx.x;
  for (; i < 5242880; i += 2048 * 256) {
    const float* s; bf16* d; int off;
    if (i < NX)            { s = x;  d = xo;  off = i; }
    else if (i < NX + NA)  { s = wa; d = wao; off = i - NX; }
    else                   { s = wp; d = wpo; off = i - NX - NA; }
    float4 v = reinterpret_cast<const float4*>(s)[off];
    bf16x4 o;
    o[0] = (bf16)v.x; o[1] = (bf16)v.y; o[2] = (bf16)v.z; o[3] = (bf16)v.w;
    reinterpret_cast<bf16x4*>(d)[off] = o;
  }
}

// ============ 128x384 fat-phase GEMM: C = A(MxK) @ B(NxK)^T + bias ============
template <typename OutT>
__global__ __launch_bounds__(512, 2) void gemm384_bt_bias(
    const bf16* __restrict__ A, const bf16* __restrict__ B,
    const float* __restrict__ bias, OutT* __restrict__ C,
    int M, int N, int K)
{
  __shared__ __align__(16) bf16 Asl[2][128 * 64];  // 32 KB
  __shared__ __align__(16) bf16 Bsl[2][384 * 64];  // 96 KB
  const int tid = threadIdx.x;
  const int lane = tid & 63;
  const int wv = tid >> 6;          // 0..7
  const int g = lane >> 4, r16 = lane & 15;
  const int wm = wv >> 2;           // 0..1 : 64-row slice
  const int wn = wv & 3;            // 0..3 : 96-col slice

  int bid = blockIdx.x;
  int bid2 = (bid & 7) * (gridDim.x >> 3) + (bid >> 3);
  const int ntn = N / 384;
  const int bn = bid2 % ntn, bm = bid2 / ntn;

  const size_t Abase = (size_t)(bm * 128) * K;
  const size_t Bbase = (size_t)(bn * 384) * K;

  f32x4 acc[2][2][2][3] = {};          // [qr][qc][R][F]
  bf16x8 a0[2][2], a1[2][2];           // A row-halves  [R][ks]
  bf16x8 b0[3][2], b1[3][2];           // B col-halves  [F][ks]

  auto stageA = [&](int bb, int t) {
#pragma unroll
    for (int i = 0; i < 2; ++i) {
      int c = i * 512 + tid;
      int r = c >> 3, p = c & 7, j = p ^ (r & 7);
      gload_lds16(A + Abase + (size_t)r * K + t * 64 + j * 8,
                  (char*)&Asl[bb][0] + (size_t)c * 16);
    }
  };
  auto stageB = [&](int bb, int u, int t) {   // u = 0..2 -> B rows u*128..+127
#pragma unroll
    for (int i = 0; i < 2; ++i) {
      int c = i * 512 + tid;
      int r = c >> 3, p = c & 7, j = p ^ (r & 7);
      gload_lds16(B + Bbase + (size_t)(u * 128 + r) * K + t * 64 + j * 8,
                  (char*)&Bsl[bb][0] + u * 16384 + (size_t)c * 16);
    }
  };
  auto readAh = [&](bf16x8 (&dst)[2][2], int bufi, int qr) {
#pragma unroll
    for (int R = 0; R < 2; ++R) {
      int ar = wm * 64 + qr * 32 + R * 16 + r16;
#pragma unroll
      for (int ks = 0; ks < 2; ++ks)
        dst[R][ks] = *reinterpret_cast<const bf16x8*>(
            &Asl[bufi][ar * 64 + (((ks * 4 + g) ^ (ar & 7)) << 3)]);
    }
  };
  auto readBh = [&](bf16x8 (&dst)[3][2], int bufi, int qc) {
#pragma unroll
    for (int F = 0; F < 3; ++F) {
      int br = wn * 96 + qc * 48 + F * 16 + r16;
#pragma unroll
      for (int ks = 0; ks < 2; ++ks)
        dst[F][ks] = *reinterpret_cast<const bf16x8*>(
            &Bsl[bufi][br * 64 + (((ks * 4 + g) ^ (br & 7)) << 3)]);
    }
  };
  auto mfma12 = [&](f32x4 (&cq)[2][3], bf16x8 (&aa)[2][2], bf16x8 (&bb)[3][2]) {
#pragma unroll
    for (int ks = 0; ks < 2; ++ks)
#pragma unroll
      for (int R = 0; R < 2; ++R)
#pragma unroll
        for (int F = 0; F < 3; ++F)
          cq[R][F] = __builtin_amdgcn_mfma_f32_16x16x32_bf16(aa[R][ks], bb[F][ks], cq[R][F], 0, 0, 0);
  };

  stageA(0, 0); stageB(0, 0, 0); stageB(0, 1, 0); stageB(0, 2, 0);
  __syncthreads();

  const int NT = K >> 6;
  for (int t = 0; t < NT; ++t) {
    const int cb = t & 1, nb = cb ^ 1;
    if (t + 1 < NT) {
      stageA(nb, t + 1); stageB(nb, 0, t + 1); stageB(nb, 1, t + 1); stageB(nb, 2, t + 1);
    }
    readAh(a0, cb, 0); readAh(a1, cb, 1);
    readBh(b0, cb, 0); readBh(b1, cb, 1);
    mfma12(acc[0][0], a0, b0);
    mfma12(acc[0][1], a0, b1);
    mfma12(acc[1][1], a1, b1);
    mfma12(acc[1][0], a1, b0);
    __syncthreads();
  }

#pragma unroll
  for (int qr = 0; qr < 2; ++qr)
#pragma unroll
    for (int qc = 0; qc < 2; ++qc)
#pragma unroll
      for (int R = 0; R < 2; ++R)
#pragma unroll
        for (int F = 0; F < 3; ++F) {
          int row0 = bm * 128 + wm * 64 + qr * 32 + R * 16 + g * 4;
          int col  = bn * 384 + wn * 96 + qc * 48 + F * 16 + r16;
          float bv = bias[col];
#pragma unroll
          for (int rr = 0; rr < 4; ++rr)
            C[(size_t)(row0 + rr) * N + col] = (OutT)(acc[qr][qc][R][F][rr] + bv);
        }
}

// ---------------- 128x128 fat-phase GEMM (BK=64 dbuf, 2 blocks/CU): fp32 out --------
__global__ __launch_bounds__(256, 2) void gemm_bt_bias(
    const bf16* __restrict__ A, const bf16* __restrict__ B,
    const float* __restrict__ bias, float* __restrict__ C,
    int M, int N, int K)
{
  __shared__ __align__(16) bf16 As[2][128 * 64];  // 32 KB
  __shared__ __align__(16) bf16 Bs[2][128 * 64];  // 32 KB
  const int tid = threadIdx.x;
  const int lane = tid & 63;
  const int w = tid >> 6;
  const int wm = (w >> 1) * 64, wn = (w & 1) * 64;
  const int g = lane >> 4;
  const int r16 = lane & 15;

  int lb = blockIdx.y * gridDim.x + blockIdx.x;
  int nblk = gridDim.x * gridDim.y;
  int s = (lb & 7) * (nblk >> 3) + (lb >> 3);
  const int bn = s % gridDim.x, bm = s / gridDim.x;

  f32x4 acc[4][4] = {};

  const size_t Abase = (size_t)(bm * 128) * K;
  const size_t Bbase = (size_t)(bn * 128) * K;

  auto stage = [&](int bb, int t) {
#pragma unroll
    for (int i = 0; i < 4; ++i) {
      int c = i * 256 + tid;
      int r = c >> 3, p = c & 7, j = p ^ (r & 7);
      gload_lds16(A + Abase + (size_t)r * K + t * 64 + j * 8,
                  (char*)&As[bb][0] + (size_t)c * 16);
      gload_lds16(B + Bbase + (size_t)r * K + t * 64 + j * 8,
                  (char*)&Bs[bb][0] + (size_t)c * 16);
    }
  };

  stage(0, 0);
  __syncthreads();

  const int NT = K >> 6;
  for (int t = 0; t < NT; ++t) {
    const int cb = t & 1, nb = cb ^ 1;
    if (t + 1 < NT) stage(nb, t + 1);
    bf16x8 a[4][2], b[4][2];
#pragma unroll
    for (int m = 0; m < 4; ++m) {
      int ar = wm + m * 16 + r16;
#pragma unroll
      for (int ks = 0; ks < 2; ++ks)
        a[m][ks] = *reinterpret_cast<const bf16x8*>(
            &As[cb][ar * 64 + (((ks * 4 + g) ^ (ar & 7)) << 3)]);
    }
#pragma unroll
    for (int n = 0; n < 4; ++n) {
      int br = wn + n * 16 + r16;
#pragma unroll
      for (int ks = 0; ks < 2; ++ks)
        b[n][ks] = *reinterpret_cast<const bf16x8*>(
            &Bs[cb][br * 64 + (((ks * 4 + g) ^ (br & 7)) << 3)]);
    }
#pragma unroll
    for (int ks = 0; ks < 2; ++ks)
#pragma unroll
      for (int m = 0; m < 4; ++m)
#pragma unroll
        for (int n = 0; n < 4; ++n)
          acc[m][n] = __builtin_amdgcn_mfma_f32_16x16x32_bf16(a[m][ks], b[n][ks], acc[m][n], 0, 0, 0);
    __syncthreads();
  }

#pragma unroll
  for (int m = 0; m < 4; ++m) {
    int row0 = bm * 128 + wm + m * 16 + g * 4;
#pragma unroll
    for (int n = 0; n < 4; ++n) {
      int col = bn * 128 + wn + n * 16 + r16;
      float bv = bias[col];
#pragma unroll
      for (int rr = 0; rr < 4; ++rr)
        C[(size_t)(row0 + rr) * N + col] = acc[m][n][rr] + bv;
    }
  }
}

// -------- fused LayerNorm+RoPE (blocks 0..4095) + V transpose (blocks 4096..8191) ----
// G13-vectorized: LN = 2 rows/wave, 32 lanes/row, bf16x4 (8B/lane) loads+stores,
// float4 weight loads, half-wave shfl reduce. Transpose = bf16x4 global loads -> LDS
// [32][36] (8B-aligned rows) -> bf16x4 global stores.
__global__ __launch_bounds__(256) void lnrope_vt_kernel(
    const bf16* __restrict__ qkv, const float* __restrict__ qw,
    const float* __restrict__ kw, bf16* __restrict__ qo, bf16* __restrict__ ko,
    bf16* __restrict__ vt)
{
  __shared__ bf16 tile[32][36];
  const int tid = threadIdx.x;
  if (blockIdx.x < 4096) {
    const int lane = tid & 63;
    const int wid = blockIdx.x * 4 + (tid >> 6);   // 0..16383
    const int rid = wid * 2 + (lane >> 5);         // 0..32767
    const int h = rid >> 11;
    const int t = rid & (T_DIM - 1);
    const int c0 = (lane & 31) * 4;

    float if0 = exp2f(-13.287712379549449f * (float)c0 * (1.0f / 128.0f));
    float if1 = exp2f(-13.287712379549449f * (float)(c0 + 2) * (1.0f / 128.0f));
    float fr0 = (float)t * if0, fr1 = (float)t * if1;
    float sn0 = sinf(fr0), cs0 = cosf(fr0);
    float sn1 = sinf(fr1), cs1 = cosf(fr1);
    const float scaleq = 0.08838834764831845f; // 1/sqrt(128)

#pragma unroll
    for (int which = 0; which < 2; ++which) {
      const bf16* base = qkv + (size_t)t * (3 * D_DIM) + which * D_DIM + h * C_DIM + c0;
      bf16x4 v4 = *reinterpret_cast<const bf16x4*>(base);
      float x0 = (float)v4[0], x1 = (float)v4[1], x2 = (float)v4[2], x3 = (float)v4[3];
      float s = x0 + x1 + x2 + x3;
#pragma unroll
      for (int m = 16; m; m >>= 1) s += __shfl_xor(s, m);
      float mu = s * (1.0f / 128.0f);
      float d0 = x0 - mu, d1 = x1 - mu, d2 = x2 - mu, d3 = x3 - mu;
      float ss = d0 * d0 + d1 * d1 + d2 * d2 + d3 * d3;
#pragma unroll
      for (int m = 16; m; m >>= 1) ss += __shfl_xor(ss, m);
      float rstd = rsqrtf(ss * (1.0f / 128.0f) + 1e-6f);
      const float* wgt = which ? kw : qw;
      float4 wv = *reinterpret_cast<const float4*>(wgt + c0);
      float y0 = d0 * rstd * wv.x, y1 = d1 * rstd * wv.y;
      float y2 = d2 * rstd * wv.z, y3 = d3 * rstd * wv.w;
      float o0 = y0 * cs0 - y1 * sn0;
      float o1 = y1 * cs0 + y0 * sn0;
      float o2 = y2 * cs1 - y3 * sn1;
      float o3 = y3 * cs1 + y2 * sn1;
      if (!which) { o0 *= scaleq; o1 *= scaleq; o2 *= scaleq; o3 *= scaleq; }
      bf16x4 ob; ob[0] = (bf16)o0; ob[1] = (bf16)o1; ob[2] = (bf16)o2; ob[3] = (bf16)o3;
      *reinterpret_cast<bf16x4*>(
          (which ? ko : qo) + ((size_t)h * T_DIM + t) * C_DIM + c0) = ob;
    }
  } else {
    const int vb = blockIdx.x - 4096;          // 64 x 4 x 16
    const int t0 = (vb & 63) * 32;
    const int c0 = ((vb >> 6) & 3) * 32;
    const int h = vb >> 8;
    {
      int row = tid >> 3, col4 = (tid & 7) * 4;
      *reinterpret_cast<bf16x4*>(&tile[row][col4]) =
          *reinterpret_cast<const bf16x4*>(
              &qkv[(size_t)(t0 + row) * (3 * D_DIM) + 2 * D_DIM + h * C_DIM + c0 + col4]);
    }
    __syncthreads();
    {
      int c = tid >> 3, t4 = (tid & 7) * 4;
      bf16x4 ob;
      ob[0] = tile[t4][c];     ob[1] = tile[t4 + 1][c];
      ob[2] = tile[t4 + 2][c]; ob[3] = tile[t4 + 3][c];
      *reinterpret_cast<bf16x4*>(
          &vt[((size_t)h * C_DIM + c0 + c) * T_DIM + t0 + t4]) = ob;
    }
  }
}

// ------- Flash attention (causal): R8 measured-best body (55.2 us) -------
// 256 thr, 4 blocks/CU (36 KB LDS, 56 VGPR). Blocks: x in [0,48), y = head.
//   b <  32: qb = 16+(b>>1), sp=b&1: KV tiles [sp?32:0, sp?2qb+2:32) -> partial U/ML
//   b >= 32: qb = 47-b, full range [0, 2qb+2) -> direct AO
// NOTE (R10/R15 lesson): this 56-VGPR body supports AT MOST 4 waves/SIMD; requesting
// more makes the allocator clamp to 32 VGPR and spill catastrophically.
__global__ __launch_bounds__(256, 4) void attn_kernel(
    const bf16* __restrict__ Q, const bf16* __restrict__ K,
    const bf16* __restrict__ VT, bf16* __restrict__ AO,
    float* __restrict__ U, float* __restrict__ ML)
{
  __shared__ __align__(16) bf16 Ks[2][32 * 128];   // 16 KB
  __shared__ __align__(16) bf16 Vs[2][128 * 32];   // 16 KB
  __shared__ __align__(16) bf16 p_lds[4][16 * 32]; //  4 KB
  const int tid = threadIdx.x;
  const int lane = tid & 63;
  const int w = tid >> 6;
  const int g = lane >> 4, r16 = lane & 15;
  const int h = blockIdx.y;
  const int b = blockIdx.x;

  int qb, kb0, kb1, sp;
  if (b < 32) { qb = 16 + (b >> 1); sp = b & 1; kb0 = sp * 32; kb1 = sp ? (2 * qb + 2) : 32; }
  else        { qb = 47 - b;        sp = -1;    kb0 = 0;       kb1 = 2 * qb + 2; }
  const int qr0 = qb * 64 + w * 16;
  const int qrow = qr0 + r16;   // this lane's q-row

  const bf16* Qh = Q + (size_t)h * T_DIM * C_DIM;
  const bf16* Kh = K + (size_t)h * T_DIM * C_DIM;
  const bf16* Vh = VT + (size_t)h * C_DIM * T_DIM;

  bf16x8 qf[4];
#pragma unroll
  for (int kk = 0; kk < 4; ++kk)
    qf[kk] = *reinterpret_cast<const bf16x8*>(
        &Qh[(size_t)qrow * C_DIM + kk * 32 + g * 8]);

  float mrow = -INFINITY, lrow = 0.f;
  f32x4 o[8] = {};

  auto stage = [&](int bb, int kb) {
    const bf16* Kt = Kh + (size_t)(kb * 32) * C_DIM;
    const bf16* Vt = Vh + kb * 32;
#pragma unroll
    for (int i = 0; i < 2; ++i) {
      int e = i * 256 + tid;
      int r = e >> 4, p = e & 15, j = p ^ (r & 7);
      gload_lds16(Kt + r * C_DIM + j * 8, (char*)&Ks[bb][0] + (size_t)e * 16);
    }
#pragma unroll
    for (int i = 0; i < 2; ++i) {
      int e = i * 256 + tid;
      int r = e >> 2, p = e & 3, j = p ^ ((r >> 1) & 3);
      gload_lds16(Vt + (size_t)r * T_DIM + j * 8, (char*)&Vs[bb][0] + (size_t)e * 16);
    }
  };

  stage(0, kb0);
  __syncthreads();
  int buf = 0;

  for (int kb = kb0; kb < kb1; ++kb) {
    if (kb + 1 < kb1) stage(buf ^ 1, kb + 1);

    f32x4 sacc[2] = {};
    __builtin_amdgcn_s_setprio(1);
#pragma unroll
    for (int n = 0; n < 2; ++n) {
      int kr = n * 16 + r16;
      const bf16* kbase = &Ks[buf][kr << 7];
#pragma unroll
      for (int kk = 0; kk < 4; ++kk) {
        bf16x8 kf = *reinterpret_cast<const bf16x8*>(
            kbase + (((kk * 4 + g) ^ (kr & 7)) << 3));
        sacc[n] = __builtin_amdgcn_mfma_f32_16x16x32_bf16(kf, qf[kk], sacc[n], 0, 0, 0);
      }
    }
    __builtin_amdgcn_s_setprio(0);
    if (kb * 32 + 31 > qr0) {
#pragma unroll
      for (int n = 0; n < 2; ++n)
#pragma unroll
        for (int rr = 0; rr < 4; ++rr)
          if (kb * 32 + n * 16 + g * 4 + rr > qrow) sacc[n][rr] = -3.0e38f;
    }
    float mx = fmaxf(fmaxf(fmaxf(sacc[0][0], sacc[0][1]), fmaxf(sacc[0][2], sacc[0][3])),
                     fmaxf(fmaxf(sacc[1][0], sacc[1][1]), fmaxf(sacc[1][2], sacc[1][3])));
    mx = fmaxf(mx, __shfl_xor(mx, 16));
    mx = fmaxf(mx, __shfl_xor(mx, 32));
    float alpha = 1.0f;
    bool need = __any(mx > mrow + 8.0f);  // T13 defer-rescale
    if (need) {
      float mnew = fmaxf(mrow, mx);
      alpha = __expf(mrow - mnew);
      mrow = mnew;
    }
    float ps = 0.f;
#pragma unroll
    for (int n = 0; n < 2; ++n)
#pragma unroll
      for (int rr = 0; rr < 4; ++rr) {
        float p = __expf(sacc[n][rr] - mrow);
        sacc[n][rr] = p;
        ps += p;
      }
    ps += __shfl_xor(ps, 16);
    ps += __shfl_xor(ps, 32);
    lrow = lrow * alpha + ps;
    if (need) {
#pragma unroll
      for (int nc = 0; nc < 8; ++nc)
#pragma unroll
        for (int rr = 0; rr < 4; ++rr)
          o[nc][rr] *= alpha;
    }
    {
      bf16* prow = &p_lds[w][r16 << 5];
      const int ssw = (r16 >> 1) & 3;
#pragma unroll
      for (int n = 0; n < 2; ++n) {
        bf16x4 pk;
        pk[0] = (bf16)sacc[n][0]; pk[1] = (bf16)sacc[n][1];
        pk[2] = (bf16)sacc[n][2]; pk[3] = (bf16)sacc[n][3];
        int c8 = 2 * n + (g >> 1);
        *reinterpret_cast<bf16x4*>(prow + (((c8 ^ ssw) << 3) | ((g & 1) << 2))) = pk;
      }
    }
    asm volatile("s_waitcnt lgkmcnt(0)" ::: "memory");
    __builtin_amdgcn_s_setprio(1);
    bf16x8 pf = *reinterpret_cast<const bf16x8*>(
        &p_lds[w][(r16 << 5) + ((g ^ ((r16 >> 1) & 3)) << 3)]);
#pragma unroll
    for (int nc = 0; nc < 8; ++nc) {
      int vr = nc * 16 + r16;
      bf16x8 vf = *reinterpret_cast<const bf16x8*>(
          &Vs[buf][(vr << 5) + ((g ^ ((vr >> 1) & 3)) << 3)]);
      o[nc] = __builtin_amdgcn_mfma_f32_16x16x32_bf16(vf, pf, o[nc], 0, 0, 0);
    }
    __builtin_amdgcn_s_setprio(0);
    __syncthreads();
    buf ^= 1;
  }

  if (sp < 0) {
    float inv = 1.0f / lrow;
    bf16* arow = &AO[(size_t)qrow * D_DIM + h * C_DIM + (g << 2)];
#pragma unroll
    for (int nc = 0; nc < 8; ++nc) {
      bf16x4 ob;
      ob[0] = (bf16)(o[nc][0] * inv); ob[1] = (bf16)(o[nc][1] * inv);
      ob[2] = (bf16)(o[nc][2] * inv); ob[3] = (bf16)(o[nc][3] * inv);
      *reinterpret_cast<bf16x4*>(arow + nc * 16) = ob;
    }
  } else {
    const int qi = qb - 16;
    const size_t ubase = ((size_t)(h * 16 + qi) * 2 + sp) * (64 * 128);
    const size_t mlbase = (size_t)(h * 16 + qi) * 256 + sp * 128;
    const int row = w * 16 + r16;
    float* urow = &U[ubase + (size_t)row * 128 + (g << 2)];
#pragma unroll
    for (int nc = 0; nc < 8; ++nc)
      *reinterpret_cast<f32x4*>(urow + nc * 16) = o[nc];
    if (g == 0) {
      ML[mlbase + row] = mrow;
      ML[mlbase + 64 + row] = lrow;
    }
  }
}

// ---------------- combine: merge the two KV-split partials for qb>=16 ----------------
__global__ __launch_bounds__(256) void attn_combine(
    const float* __restrict__ U, const float* __restrict__ ML, bf16* __restrict__ AO)
{
  int idx = blockIdx.x * 256 + threadIdx.x;
  int c4 = (idx & 31) * 4;
  int r = idx >> 5;
  int trow = r & 63;
  int qi = (r >> 6) & 15;
  int h = r >> 10;

  size_t mlbase = (size_t)(h * 16 + qi) * 256;
  float m0 = ML[mlbase + trow],       l0 = ML[mlbase + 64 + trow];
  float m1 = ML[mlbase + 128 + trow], l1 = ML[mlbase + 192 + trow];
  float m = fmaxf(m0, m1);
  float a0 = __expf(m0 - m), a1 = __expf(m1 - m);
  float inv = 1.0f / (l0 * a0 + l1 * a1);

  size_t t0 = ((size_t)(h * 16 + qi) * 2) * (64 * 128) + (size_t)trow * 128 + c4;
  float4 u0 = *reinterpret_cast<const float4*>(U + t0);
  float4 u1 = *reinterpret_cast<const float4*>(U + t0 + 64 * 128);
  int t = 1024 + qi * 64 + trow;
  bf16x4 ob;
  ob[0] = (bf16)((u0.x * a0 + u1.x * a1) * inv);
  ob[1] = (bf16)((u0.y * a0 + u1.y * a1) * inv);
  ob[2] = (bf16)((u0.z * a0 + u1.z * a1) * inv);
  ob[3] = (bf16)((u0.w * a0 + u1.w * a1) * inv);
  *reinterpret_cast<bf16x4*>(&AO[(size_t)t * D_DIM + h * C_DIM + c4]) = ob;
}

// ---------------- launch ----------------
extern "C" void kernel_launch(void* const* d_in, const int* in_sizes, int n_in,
                              void* d_out, int out_size, void* d_ws, size_t ws_size,
                              hipStream_t stream)
{
  const float* x      = (const float*)d_in[0];
  const float* W_attn = (const float*)d_in[1];
  const float* b_attn = (const float*)d_in[2];
  const float* W_proj = (const float*)d_in[3];
  const float* b_proj = (const float*)d_in[4];
  const float* q_ln_w = (const float*)d_in[5];
  const float* k_ln_w = (const float*)d_in[6];

  char* ws = (char*)d_ws;
  bf16*  x_bf  = (bf16*)(ws + 0);           //  8 MB
  bf16*  wa_bf = (bf16*)(ws + 8388608);     // 24 MB
  bf16*  wp_bf = (bf16*)(ws + 33554432);    //  8 MB
  bf16*  qkv   = (bf16*)(ws + 41943040);    // 24 MB (bf16; dead after lnrope_vt)
  float* U     = (float*)(ws + 67108864);   // 16 MB
  float* ML    = (float*)(ws + 83886080);   // 256 KB
  bf16*  q_bf  = (bf16*)(ws + 92274688);    //  8 MB
  bf16*  k_bf  = (bf16*)(ws + 100663296);   //  8 MB
  bf16*  vt    = (bf16*)(ws + 109051904);   //  8 MB
  bf16*  ao    = (bf16*)(ws + 117440512);   //  8 MB (total 120 MB)

  cvt3<<<2048, 256, 0, stream>>>(x, W_attn, W_proj, x_bf, wa_bf, wp_bf);

  gemm384_bt_bias<bf16><<<dim3((T_DIM / 128) * (3 * D_DIM / 384)), dim3(512), 0, stream>>>(
      x_bf, wa_bf, b_attn, qkv, T_DIM, 3 * D_DIM, D_DIM);

  lnrope_vt_kernel<<<4096 + 4096, 256, 0, stream>>>(qkv, q_ln_w, k_ln_w, q_bf, k_bf, vt);

  attn_kernel<<<dim3(48, H_DIM), 256, 0, stream>>>(q_bf, k_bf, vt, ao, U, ML);
  attn_combine<<<2048, 256, 0, stream>>>(U, ML, ao);

  gemm_bt_bias<<<dim3(D_DIM / 128, T_DIM / 128), 256, 0, stream>>>(
      ao, wp_bf, b_proj, (float*)d_out, T_DIM, D_DIM, D_DIM);
}